// Round 15
// baseline (220.801 us; speedup 1.0000x reference)
//
#include <hip/hip_runtime.h>
#include <stdint.h>

#define D_MODEL 512
#define D_STATE 16
#define DT_RANK 32
#define SEQ 2048
#define NBATCH 4
#define FN 32
#define CHUNK 16
#define NCHUNK 128   // SEQ / CHUNK
#define DPPLANE ((size_t)8192*D_MODEL)   // one split-K partial plane (elements)

typedef unsigned short u16;
using s16x8 = __attribute__((ext_vector_type(8))) short;
using f32x4 = __attribute__((ext_vector_type(4))) float;
using f32x8 = __attribute__((ext_vector_type(8))) float;
using bf16x8 = __attribute__((ext_vector_type(8))) __bf16;

typedef __attribute__((address_space(3))) void lds_void;
typedef __attribute__((address_space(1))) const void glb_void;

__device__ __forceinline__ void gload16(const void* g, void* l) {
  __builtin_amdgcn_global_load_lds((glb_void*)g, (lds_void*)l, 16, 0, 0);
}

__device__ inline u16 f2bf(float f) {
  uint32_t u = __float_as_uint(f);
  u += 0x7FFFu + ((u >> 16) & 1u);   // RNE
  return (u16)(u >> 16);
}
__device__ __forceinline__ float bf2f(u16 v) {
  return __uint_as_float((uint32_t)v << 16);
}

// HW packed convert: 2×float4 -> 8 bf16 (v_cvt_pk_bf16_f32, RNE)
__device__ __forceinline__ s16x8 pack8bf(float4 lo, float4 hi) {
  f32x8 v;
  v[0] = lo.x; v[1] = lo.y; v[2] = lo.z; v[3] = lo.w;
  v[4] = hi.x; v[5] = hi.y; v[6] = hi.z; v[7] = hi.w;
  bf16x8 b = __builtin_convertvector(v, bf16x8);
  return __builtin_bit_cast(s16x8, b);
}
__device__ __forceinline__ ushort4 pack4bf(float a, float b, float c, float d) {
  ushort4 o; o.x = f2bf(a); o.y = f2bf(b); o.z = f2bf(c); o.w = f2bf(d);
  return o;
}

// ---------------- FiLM stage 1: h = silu(gpt @ w1^T + b1) ----------------
__global__ __launch_bounds__(256) void film1_kernel(
    const float* __restrict__ gpt, const float* __restrict__ w1,
    const float* __restrict__ b1, float* __restrict__ h)
{
  int b = blockIdx.y, r0 = blockIdx.x*16, t = threadIdx.x;
  __shared__ float g[D_MODEL];
  for (int i = t; i < D_MODEL; i += 256) g[i] = gpt[b*D_MODEL + i];
  __syncthreads();
  int r = r0 + (t >> 4), ln = t & 15;
  const float* wr = &w1[(size_t)r*D_MODEL + ln*32];
  const float* gg = &g[ln*32];
  float s = 0.f;
  #pragma unroll
  for (int k = 0; k < 32; k += 4) {
    float4 w = *(const float4*)&wr[k];
    s += w.x*gg[k] + w.y*gg[k+1] + w.z*gg[k+2] + w.w*gg[k+3];
  }
  s += __shfl_down(s, 8); s += __shfl_down(s, 4);
  s += __shfl_down(s, 2); s += __shfl_down(s, 1);
  if (ln == 0) { float v = s + b1[r]; h[b*D_MODEL + r] = v / (1.f + expf(-v)); }
}

// ---------------- FiLM stage 2: gb = h @ w2^T + b2 (gamma|beta) ----------------
__global__ __launch_bounds__(256) void film2_kernel(
    const float* __restrict__ h, const float* __restrict__ w2,
    const float* __restrict__ b2, float* __restrict__ gb)
{
  int b = blockIdx.y, r0 = blockIdx.x*16, t = threadIdx.x;
  __shared__ float hs[D_MODEL];
  for (int i = t; i < D_MODEL; i += 256) hs[i] = h[b*D_MODEL + i];
  __syncthreads();
  int r = r0 + (t >> 4), ln = t & 15;
  const float* wr = &w2[(size_t)r*D_MODEL + ln*32];
  const float* gg = &hs[ln*32];
  float s = 0.f;
  #pragma unroll
  for (int k = 0; k < 32; k += 4) {
    float4 w = *(const float4*)&wr[k];
    s += w.x*gg[k] + w.y*gg[k+1] + w.z*gg[k+2] + w.w*gg[k+3];
  }
  s += __shfl_down(s, 8); s += __shfl_down(s, 4);
  s += __shfl_down(s, 2); s += __shfl_down(s, 1);
  if (ln == 0) gb[b*1024 + r] = s + b2[r];
}

// ---------------- merged prep: fgpad | inwbf | outwbf | wcomb | dis->bf16 ----------------
__global__ __launch_bounds__(256) void prep_kernel(
    const float* __restrict__ fg, const float* __restrict__ inw,
    const float* __restrict__ outw, const float* __restrict__ dtw,
    const float* __restrict__ xpw, const float* __restrict__ dis,
    u16* __restrict__ fgpad, u16* __restrict__ inwbf,
    u16* __restrict__ outwbf, u16* __restrict__ wcomb,
    u16* __restrict__ disbf)
{
  int blk = blockIdx.x, t = threadIdx.x;
  if (blk >= 2688) {                     // dis f32 -> bf16, 16384 blocks
    size_t i = (size_t)(blk - 2688)*256 + t;
    float4 v = *(const float4*)&dis[i*4];
    ushort4 o; o.x = f2bf(v.x); o.y = f2bf(v.y); o.z = f2bf(v.z); o.w = f2bf(v.w);
    *(ushort4*)&disbf[i*4] = o;
  } else if (blk < 512) {                // fgpad: [b][128][512], zero-padded
    int row = blk & 127, b = blk >> 7;
    u16* dst = &fgpad[((size_t)b*128 + row)*D_MODEL];
    if (row < FN) {
      const float* src = &fg[((size_t)b*FN + row)*D_MODEL];
      float2 v = *(const float2*)&src[t*2];
      dst[t*2] = f2bf(v.x); dst[t*2+1] = f2bf(v.y);
    } else {
      dst[t*2] = 0; dst[t*2+1] = 0;
    }
  } else if (blk < 1536) {               // inwbf
    int row = blk - 512;
    float2 v = *(const float2*)&inw[(size_t)row*D_MODEL + t*2];
    inwbf[(size_t)row*D_MODEL + t*2]     = f2bf(v.x);
    inwbf[(size_t)row*D_MODEL + t*2 + 1] = f2bf(v.y);
  } else if (blk < 2048) {               // outwbf
    int row = blk - 1536;
    float2 v = *(const float2*)&outw[(size_t)row*D_MODEL + t*2];
    outwbf[(size_t)row*D_MODEL + t*2]     = f2bf(v.x);
    outwbf[(size_t)row*D_MODEL + t*2 + 1] = f2bf(v.y);
  } else {                               // wcomb
    int row = blk - 2048;
    if (row < D_MODEL) {
      __shared__ float dr[DT_RANK];
      if (t < DT_RANK) dr[t] = dtw[row*DT_RANK + t];
      __syncthreads();
      for (int k = t; k < D_MODEL; k += 256) {
        float s = 0.f;
        #pragma unroll
        for (int r = 0; r < DT_RANK; r++) s += dr[r] * xpw[r*D_MODEL + k];
        wcomb[(size_t)row*D_MODEL + k] = f2bf(s);
      }
    } else if (row < D_MODEL + 32) {
      for (int k = t; k < D_MODEL; k += 256)
        wcomb[(size_t)row*D_MODEL + k] = f2bf(xpw[(size_t)(DT_RANK + row - D_MODEL)*D_MODEL + k]);
    } else {
      for (int k = t; k < D_MODEL; k += 256)
        wcomb[(size_t)row*D_MODEL + k] = 0;
    }
  }
}

// ---------------- softmax + PV + residual + FiLM -> x bf16, one wave per row ----------------
__global__ __launch_bounds__(256) void pv_film_kernel(
    const float* __restrict__ atoms, const float* __restrict__ fg,
    const float* __restrict__ scores, const float* __restrict__ gb,
    u16* __restrict__ xout)
{
  int wave = threadIdx.x >> 6, lane = threadIdx.x & 63;
  int row = blockIdx.x*4 + wave;           // b*SEQ + l
  int b = row >> 11;
  float s = scores[(size_t)row*128 + (lane & 31)] * 0.04419417382415922f; // 1/sqrt(512)
  float m = s;
  #pragma unroll
  for (int o = 16; o; o >>= 1) m = fmaxf(m, __shfl_xor(m, o));
  float e = __expf(s - m);
  float sum = e;
  #pragma unroll
  for (int o = 16; o; o >>= 1) sum += __shfl_xor(sum, o);
  float my_attn = e / sum;                 // attn[lane&31]

  int d0 = lane*8;
  const float* arow = &atoms[(size_t)row*D_MODEL + d0];
  float4 acc0 = *(const float4*)&arow[0];
  float4 acc1 = *(const float4*)&arow[4];
  const float* fgb = &fg[(size_t)b*FN*D_MODEL + d0];
  #pragma unroll 8
  for (int f = 0; f < FN; f++) {
    float w = __shfl(my_attn, f);          // broadcast attn[f]
    float4 g0 = *(const float4*)&fgb[(size_t)f*D_MODEL];
    float4 g1 = *(const float4*)&fgb[(size_t)f*D_MODEL + 4];
    acc0.x += w*g0.x; acc0.y += w*g0.y; acc0.z += w*g0.z; acc0.w += w*g0.w;
    acc1.x += w*g1.x; acc1.y += w*g1.y; acc1.z += w*g1.z; acc1.w += w*g1.w;
  }
  const float* gbg = &gb[(size_t)b*1024 + d0];
  float4 gm0 = *(const float4*)&gbg[0];
  float4 gm1 = *(const float4*)&gbg[4];
  float4 bt0 = *(const float4*)&gbg[D_MODEL];
  float4 bt1 = *(const float4*)&gbg[D_MODEL + 4];
  s16x8 o;
  o[0] = (short)f2bf(acc0.x*gm0.x + bt0.x);
  o[1] = (short)f2bf(acc0.y*gm0.y + bt0.y);
  o[2] = (short)f2bf(acc0.z*gm0.z + bt0.z);
  o[3] = (short)f2bf(acc0.w*gm0.w + bt0.w);
  o[4] = (short)f2bf(acc1.x*gm1.x + bt1.x);
  o[5] = (short)f2bf(acc1.y*gm1.y + bt1.y);
  o[6] = (short)f2bf(acc1.z*gm1.z + bt1.z);
  o[7] = (short)f2bf(acc1.w*gm1.w + bt1.w);
  *(s16x8*)&xout[(size_t)row*D_MODEL + d0] = o;
}

// ---------------- bf16 GEMM 64x128 tile, 2-phase dbuf; outMode: 0=f32,1=f32+clamp,2=bf16 ----------------
__global__ __launch_bounds__(256) void gemm_bt64_kernel(
    const u16* __restrict__ A, const u16* __restrict__ B, void* __restrict__ Cv_,
    int M, int N, int K, int outMode)
{
  int gx = gridDim.x, gy = gridDim.y;
  int flat = blockIdx.x + gx*blockIdx.y;
  int cpx = (gx*gy) >> 3;
  flat = (flat & 7)*cpx + (flat >> 3);
  int bx = flat % gx, by = flat / gx;
  int m0 = by * 64, n0 = bx * 128;
  __shared__ u16 As[2][64][32];
  __shared__ u16 Bs[2][128][32];
  int tid = threadIdx.x, lane = tid & 63, wave = tid >> 6;
  int wm = (wave >> 1) * 32, wn = (wave & 1) * 64;
  int fr = lane & 15, fk = (lane >> 4) * 8;
  int srow = tid >> 2, scol = (tid & 3) * 8;
  const u16* abase  = &A[(size_t)(m0 + srow)*K + scol];
  const u16* b0base = &B[(size_t)(n0 + srow)*K + scol];
  const u16* b1base = &B[(size_t)(n0 + 64 + srow)*K + scol];
  gload16(abase,  &As[0][srow][scol]);
  gload16(b0base, &Bs[0][srow][scol]);
  gload16(b1base, &Bs[0][64 + srow][scol]);
  __syncthreads();
  f32x4 acc[2][4] = {};
  int NT = K >> 5, cur = 0;
  for (int t = 0; t < NT; t++) {
    int nxt = cur ^ 1;
    if (t + 1 < NT) {
      int k0 = (t + 1) << 5;
      gload16(&abase[k0],  &As[nxt][srow][scol]);
      gload16(&b0base[k0], &Bs[nxt][srow][scol]);
      gload16(&b1base[k0], &Bs[nxt][64 + srow][scol]);
    }
    s16x8 af[2], bf[4];
    #pragma unroll
    for (int i = 0; i < 2; i++) af[i] = *(const s16x8*)(&As[cur][wm + i*16 + fr][fk]);
    #pragma unroll
    for (int i = 0; i < 4; i++) bf[i] = *(const s16x8*)(&Bs[cur][wn + i*16 + fr][fk]);
    #pragma unroll
    for (int mi = 0; mi < 2; mi++)
      #pragma unroll
      for (int ni = 0; ni < 4; ni++)
        acc[mi][ni] = __builtin_amdgcn_mfma_f32_16x16x32_bf16(af[mi], bf[ni], acc[mi][ni], 0, 0, 0);
    __syncthreads();
    cur = nxt;
  }
  int cr = (lane >> 4) * 4, cc = lane & 15;
  if (outMode == 2) {
    u16* C = (u16*)Cv_;
    #pragma unroll
    for (int mi = 0; mi < 2; mi++)
      #pragma unroll
      for (int ni = 0; ni < 4; ni++) {
        int rowb = m0 + wm + mi*16 + cr, col = n0 + wn + ni*16 + cc;
        #pragma unroll
        for (int r = 0; r < 4; r++)
          C[(size_t)(rowb + r)*N + col] = f2bf(acc[mi][ni][r]);
      }
  } else {
    float* C = (float*)Cv_;
    #pragma unroll
    for (int mi = 0; mi < 2; mi++)
      #pragma unroll
      for (int ni = 0; ni < 4; ni++) {
        int rowb = m0 + wm + mi*16 + cr, col = n0 + wn + ni*16 + cc;
        #pragma unroll
        for (int r = 0; r < 4; r++) {
          float v = acc[mi][ni][r];
          if (outMode == 1 && !isfinite(v)) v = 0.f;
          C[(size_t)(rowb + r)*N + col] = v;
        }
      }
  }
}

// ---------------- scores GEMM: fp32 A, 64-row tiles (better occupancy) ----------------
__global__ __launch_bounds__(256) void gemm_f32a64_kernel(
    const float* __restrict__ Ag, const u16* __restrict__ Bg, float* __restrict__ Cg,
    int M, int N, int K, long long azs, long long bzs, long long czs)
{
  int gx = gridDim.x, gy = gridDim.y;
  int flat = blockIdx.x + gx*(blockIdx.y + gy*blockIdx.z);
  int cpx = (gx*gy*(int)gridDim.z) >> 3;
  flat = (flat & 7)*cpx + (flat >> 3);
  int bx = flat % gx, tmp = flat / gx;
  int by = tmp % gy, bz = tmp / gy;
  const float* A = Ag + (size_t)bz * azs;
  const u16* B = Bg + (size_t)bz * bzs;
  float* C = Cg + (size_t)bz * czs;
  int m0 = by * 64, n0 = bx * 128;
  __shared__ u16 As[64][32];
  __shared__ u16 Bs[128][32];
  int tid = threadIdx.x, lane = tid & 63, wave = tid >> 6;
  int wm = (wave >> 1) * 32, wn = (wave & 1) * 64;
  int fr = lane & 15, fk = (lane >> 4) * 8;
  int srow = tid >> 2, scol = (tid & 3) * 8;
  f32x4 acc[2][4] = {};
  for (int k0 = 0; k0 < K; k0 += 32) {
    const float* ap = &A[(size_t)(m0 + srow)*K + k0 + scol];
    float4 a0 = *(const float4*)&ap[0];
    float4 a1 = *(const float4*)&ap[4];
    gload16(&B[(size_t)(n0 + srow)*K + k0 + scol],      &Bs[srow][scol]);
    gload16(&B[(size_t)(n0 + 64 + srow)*K + k0 + scol], &Bs[64 + srow][scol]);
    *(s16x8*)&As[srow][scol] = pack8bf(a0, a1);
    __syncthreads();
    s16x8 af[2], bf[4];
    #pragma unroll
    for (int i = 0; i < 2; i++) af[i] = *(const s16x8*)(&As[wm + i*16 + fr][fk]);
    #pragma unroll
    for (int i = 0; i < 4; i++) bf[i] = *(const s16x8*)(&Bs[wn + i*16 + fr][fk]);
    #pragma unroll
    for (int mi = 0; mi < 2; mi++)
      #pragma unroll
      for (int ni = 0; ni < 4; ni++)
        acc[mi][ni] = __builtin_amdgcn_mfma_f32_16x16x32_bf16(af[mi], bf[ni], acc[mi][ni], 0, 0, 0);
    __syncthreads();
  }
  int cr = (lane >> 4) * 4, cc = lane & 15;
  #pragma unroll
  for (int mi = 0; mi < 2; mi++)
    #pragma unroll
    for (int ni = 0; ni < 4; ni++) {
      int rowb = m0 + wm + mi*16 + cr, col = n0 + wn + ni*16 + cc;
      #pragma unroll
      for (int r = 0; r < 4; r++)
        C[(size_t)(rowb + r)*N + col] = acc[mi][ni][r];
    }
}

// ---------------- delta_p split-K GEMM, all-bf16, BK=64 (32KB LDS, 4 blk/CU) ----------------
__global__ __launch_bounds__(256) void gemm_dpbf_splitk_kernel(
    const u16* __restrict__ disbf, const u16* __restrict__ deltaT,
    u16* __restrict__ dpp)
{
  int gx = gridDim.x, gy = gridDim.y;
  int flat = blockIdx.x + gx*(blockIdx.y + gy*blockIdx.z);
  int cpx = (gx*gy*(int)gridDim.z) >> 3;
  flat = (flat & 7)*cpx + (flat >> 3);
  int bx = flat % gx, tmp = flat / gx;
  int by = tmp % gy, bz = tmp / gy;
  int b = bz >> 2, ks = bz & 3;
  const u16* A = disbf  + (size_t)b*SEQ*SEQ     + ks*512;
  const u16* B = deltaT + (size_t)b*D_MODEL*SEQ + ks*512;
  u16*       C = dpp    + (size_t)ks*DPPLANE    + (size_t)b*SEQ*D_MODEL;
  int m0 = by * 128, n0 = bx * 128;
  __shared__ u16 As[128][64];
  __shared__ u16 Bs[128][64];
  int tid = threadIdx.x, lane = tid & 63, wave = tid >> 6;
  int wm = (wave >> 1) * 64, wn = (wave & 1) * 64;
  int fr = lane & 15, fk = (lane >> 4) * 8;
  int srow = tid >> 3, scol = (tid & 7) * 8;     // 32 rows / issue, 64-col rows
  f32x4 acc[4][4] = {};
  for (int k0 = 0; k0 < 512; k0 += 64) {
    #pragma unroll
    for (int i = 0; i < 4; i++) {
      gload16(&A[(size_t)(m0 + srow + 32*i)*SEQ + k0 + scol], &As[srow + 32*i][scol]);
      gload16(&B[(size_t)(n0 + srow + 32*i)*SEQ + k0 + scol], &Bs[srow + 32*i][scol]);
    }
    __syncthreads();
    #pragma unroll
    for (int kk = 0; kk < 64; kk += 32) {
      s16x8 af[4], bf[4];
      #pragma unroll
      for (int i = 0; i < 4; i++) af[i] = *(const s16x8*)(&As[wm + i*16 + fr][kk + fk]);
      #pragma unroll
      for (int i = 0; i < 4; i++) bf[i] = *(const s16x8*)(&Bs[wn + i*16 + fr][kk + fk]);
      #pragma unroll
      for (int mi = 0; mi < 4; mi++)
        #pragma unroll
        for (int ni = 0; ni < 4; ni++)
          acc[mi][ni] = __builtin_amdgcn_mfma_f32_16x16x32_bf16(af[mi], bf[ni], acc[mi][ni], 0, 0, 0);
    }
    __syncthreads();
  }
  int cr = (lane >> 4) * 4, cc = lane & 15;
  #pragma unroll
  for (int mi = 0; mi < 4; mi++)
    #pragma unroll
    for (int ni = 0; ni < 4; ni++) {
      int rowb = m0 + wm + mi*16 + cr, col = n0 + wn + ni*16 + cc;
      #pragma unroll
      for (int r = 0; r < 4; r++)
        C[(size_t)(rowb + r)*D_MODEL + col] = f2bf(acc[mi][ni][r]);
    }
}

// ---------------- fused delta/B/C GEMM (64-row tiles): ubf @ Wcomb^T ----------------
__global__ __launch_bounds__(256) void gemm_delta_kernel(
    const u16* __restrict__ A, const u16* __restrict__ B,
    const float* __restrict__ dtb, u16* __restrict__ deltaT,
    float* __restrict__ Bv, float* __restrict__ Cv)
{
  int gx = gridDim.x, gy = gridDim.y;   // (5, 128)
  int flat = blockIdx.x + gx*blockIdx.y;
  int cpx = (gx*gy) >> 3;
  flat = (flat & 7)*cpx + (flat >> 3);
  int bx = flat % gx, by = flat / gx;
  int m0 = by * 64, n0 = bx * 128;
  __shared__ u16 As[64][32];
  __shared__ u16 Bs[128][32];
  int tid = threadIdx.x, lane = tid & 63, wave = tid >> 6;
  int wm = (wave >> 1) * 32, wn = (wave & 1) * 64;
  int fr = lane & 15, fk = (lane >> 4) * 8;
  int srow = tid >> 2, scol = (tid & 3) * 8;
  f32x4 acc[2][4] = {};
  for (int k0 = 0; k0 < D_MODEL; k0 += 32) {
    gload16(&A[(size_t)(m0 + srow)*D_MODEL + k0 + scol],      &As[srow][scol]);
    gload16(&B[(size_t)(n0 + srow)*D_MODEL + k0 + scol],      &Bs[srow][scol]);
    gload16(&B[(size_t)(n0 + 64 + srow)*D_MODEL + k0 + scol], &Bs[64 + srow][scol]);
    __syncthreads();
    s16x8 af[2], bf[4];
    #pragma unroll
    for (int i = 0; i < 2; i++) af[i] = *(const s16x8*)(&As[wm + i*16 + fr][fk]);
    #pragma unroll
    for (int i = 0; i < 4; i++) bf[i] = *(const s16x8*)(&Bs[wn + i*16 + fr][fk]);
    #pragma unroll
    for (int mi = 0; mi < 2; mi++)
      #pragma unroll
      for (int ni = 0; ni < 4; ni++)
        acc[mi][ni] = __builtin_amdgcn_mfma_f32_16x16x32_bf16(af[mi], bf[ni], acc[mi][ni], 0, 0, 0);
    __syncthreads();
  }
  int cr = (lane >> 4) * 4, cc = lane & 15;
  #pragma unroll
  for (int mi = 0; mi < 2; mi++)
    #pragma unroll
    for (int ni = 0; ni < 4; ni++) {
      int rowb = m0 + wm + mi*16 + cr, col = n0 + wn + ni*16 + cc;
      if (col < D_MODEL) {
        float bias = dtb[col];
        #pragma unroll
        for (int r = 0; r < 4; r++) {
          float v = acc[mi][ni][r] + bias;
          v = (v > 20.f) ? v : log1pf(expf(v));
          int gr = rowb + r;
          deltaT[((size_t)(gr >> 11)*D_MODEL + col)*SEQ + (gr & (SEQ-1))] = f2bf(v);
        }
      } else if (col < D_MODEL + 16) {
        #pragma unroll
        for (int r = 0; r < 4; r++)
          Bv[(size_t)(rowb + r)*D_STATE + (col - D_MODEL)] = acc[mi][ni][r];
      } else if (col < D_MODEL + 32) {
        #pragma unroll
        for (int r = 0; r < 4; r++)
          Cv[(size_t)(rowb + r)*D_STATE + (col - D_MODEL - 16)] = acc[mi][ni][r];
      }
    }
}

// ---------------- depthwise causal conv + silu, 4 rows/thread (register reuse) ----------------
__global__ __launch_bounds__(256) void conv_silu_kernel(
    const u16* __restrict__ xsres, const float* __restrict__ cw,
    const float* __restrict__ cb, u16* __restrict__ ubf)
{
  int idx = blockIdx.x*256 + threadIdx.x;     // 262144 threads
  int dq = idx & 127;                         // d-quad
  int rg = idx >> 7;                          // row-group: rows 4rg..4rg+3
  int d = dq*4;
  size_t row0 = (size_t)rg*4;
  int l0 = (int)(row0 & (SEQ - 1));           // within-batch l of first row
  float w[4][4];
  #pragma unroll
  for (int c = 0; c < 4; c++) *(float4*)w[c] = *(const float4*)&cw[(d + c)*4];
  float4 bias = *(const float4*)&cb[d];
  float4 x[7];                                // rows l0-3 .. l0+3
  #pragma unroll
  for (int k = 0; k < 7; k++) {
    int li = l0 - 3 + k;
    if (li >= 0) {
      ushort4 v = *(const ushort4*)&xsres[(row0 - 3 + k)*1024 + d];
      x[k] = make_float4(bf2f(v.x), bf2f(v.y), bf2f(v.z), bf2f(v.w));
    } else {
      x[k] = make_float4(0.f, 0.f, 0.f, 0.f);
    }
  }
  #pragma unroll
  for (int j = 0; j < 4; j++) {
    float4 acc = bias;
    #pragma unroll
    for (int k = 0; k < 4; k++) {
      float4 v = x[j + k];
      acc.x += v.x*w[0][k]; acc.y += v.y*w[1][k];
      acc.z += v.z*w[2][k]; acc.w += v.w*w[3][k];
    }
    float4 o;
    o.x = acc.x/(1.f+expf(-acc.x)); o.y = acc.y/(1.f+expf(-acc.y));
    o.z = acc.z/(1.f+expf(-acc.z)); o.w = acc.w/(1.f+expf(-acc.w));
    ushort4 ob; ob.x = f2bf(o.x); ob.y = f2bf(o.y); ob.z = f2bf(o.z); ob.w = f2bf(o.w);
    *(ushort4*)&ubf[(row0 + j)*D_MODEL + d] = ob;
  }
}

// ---------------- scan phase A: sum bf16 split-K partials -> dpf(bf16), local state + sum(dp) ----------------
__global__ __launch_bounds__(256) void scanA_kernel(
    const u16* __restrict__ dpp, const u16* __restrict__ ubf,
    const float* __restrict__ Bv, const float* __restrict__ A_log,
    u16* __restrict__ dpf, u16* __restrict__ slocal, float* __restrict__ sumdp_out)
{
  int d = blockIdx.x*256 + threadIdx.x;
  int c = blockIdx.y, b = blockIdx.z;
  __shared__ float Bs[CHUNK][D_STATE];
  int t = threadIdx.x;
  size_t lbase = (size_t)b*SEQ + c*CHUNK;
  Bs[t >> 4][t & 15] = Bv[(lbase + (t >> 4))*D_STATE + (t & 15)];
  float a[D_STATE];
  #pragma unroll
  for (int n = 0; n < D_STATE; n += 4) {
    float4 v = *(const float4*)&A_log[(size_t)d*D_STATE + n];
    a[n] = -expf(v.x); a[n+1] = -expf(v.y); a[n+2] = -expf(v.z); a[n+3] = -expf(v.w);
  }
  __syncthreads();
  float s[D_STATE];
  #pragma unroll
  for (int n = 0; n < D_STATE; n++) s[n] = 0.f;
  float sd = 0.f;
  for (int j = 0; j < CHUNK; j++) {
    size_t r = lbase + j;
    size_t idx = r*D_MODEL + d;
    float dpv = bf2f(dpp[idx]) + bf2f(dpp[idx + DPPLANE])
              + bf2f(dpp[idx + 2*DPPLANE]) + bf2f(dpp[idx + 3*DPPLANE]);
    dpf[idx] = f2bf(dpv);
    float uv  = bf2f(ubf[idx]);
    sd += dpv;
    float dbu = dpv * uv;
    #pragma unroll
    for (int n = 0; n < D_STATE; n++)
      s[n] = __expf(a[n]*dpv)*s[n] + dbu*Bs[j][n];
  }
  size_t obase = ((size_t)b*NCHUNK + c)*D_MODEL + d;
  #pragma unroll
  for (int n = 0; n < D_STATE; n += 4)
    *(ushort4*)&slocal[obase*D_STATE + n] = pack4bf(s[n], s[n+1], s[n+2], s[n+3]);
  sumdp_out[obase] = sd;
}

// ---------------- scan phase B: propagate chunk carries (bf16 in/out), 64-thr blocks ----------------
__global__ __launch_bounds__(64) void scanB_kernel(
    const u16* __restrict__ slocal, const float* __restrict__ sumdp,
    const float* __restrict__ A_log, u16* __restrict__ sIn)
{
  int g = blockIdx.x*64 + threadIdx.x;    // 32768 = b*8192 + d*16 + n
  int n = g & 15, d = (g >> 4) & (D_MODEL - 1), b = g >> 13;
  float a = -expf(A_log[d*D_STATE + n]);
  float s = 0.f;
  for (int c = 0; c < NCHUNK; c++) {
    size_t idx = ((size_t)b*NCHUNK + c)*D_MODEL + d;
    sIn[idx*D_STATE + n] = f2bf(s);
    s = __expf(a * sumdp[idx]) * s + bf2f(slocal[idx*D_STATE + n]);
  }
}

// ---------------- scan phase C: outputs + gating, writes y bf16 ----------------
__global__ __launch_bounds__(256) void scanC_kernel(
    const u16* __restrict__ dp, const u16* __restrict__ ubf,
    const float* __restrict__ Bv, const float* __restrict__ Cv,
    const float* __restrict__ A_log, const float* __restrict__ Dp,
    const u16* __restrict__ xsres, const u16* __restrict__ sIn,
    u16* __restrict__ yout)
{
  int d = blockIdx.x*256 + threadIdx.x;
  int c = blockIdx.y, b = blockIdx.z;
  __shared__ float Bs[CHUNK][D_STATE];
  __shared__ float Cs[CHUNK][D_STATE];
  int t = threadIdx.x;
  size_t lbase = (size_t)b*SEQ + c*CHUNK;
  Bs[t >> 4][t & 15] = Bv[(lbase + (t >> 4))*D_STATE + (t & 15)];
  Cs[t >> 4][t & 15] = Cv[(lbase + (t >> 4))*D_STATE + (t & 15)];
  float a[D_STATE];
  #pragma unroll
  for (int n = 0; n < D_STATE; n += 4) {
    float4 v = *(const float4*)&A_log[(size_t)d*D_STATE + n];
    a[n] = -expf(v.x); a[n+1] = -expf(v.y); a[n+2] = -expf(v.z); a[n+3] = -expf(v.w);
  }
  float s[D_STATE];
  size_t ibase = (((size_t)b*NCHUNK + c)*D_MODEL + d)*D_STATE;
  #pragma unroll
  for (int n = 0; n < D_STATE; n += 4) {
    ushort4 v = *(const ushort4*)&sIn[ibase + n];
    s[n] = bf2f(v.x); s[n+1] = bf2f(v.y); s[n+2] = bf2f(v.z); s[n+3] = bf2f(v.w);
  }
  float dparam = Dp[d];
  __syncthreads();
  for (int j = 0; j < CHUNK; j++) {
    size_t r = lbase + j;
    float dpv = bf2f(dp[r*D_MODEL + d]);
    float uv  = bf2f(ubf[r*D_MODEL + d]);
    float dbu = dpv * uv;
    float y = 0.f;
    #pragma unroll
    for (int n = 0; n < D_STATE; n++) {
      s[n] = __expf(a[n]*dpv)*s[n] + dbu*Bs[j][n];
      y += s[n]*Cs[j][n];
    }
    y += uv * dparam;
    float rr = bf2f(xsres[r*1024 + D_MODEL + d]);
    y *= rr/(1.f + __expf(-rr));       // silu(res)
    yout[r*D_MODEL + d] = f2bf(y);
  }
}

extern "C" void kernel_launch(void* const* d_in, const int* in_sizes, int n_in,
                              void* d_out, int out_size, void* d_ws, size_t ws_size,
                              hipStream_t stream)
{
  const float* atoms  = (const float*)d_in[0];
  const float* dis    = (const float*)d_in[1];
  const float* gpt    = (const float*)d_in[2];
  const float* fg     = (const float*)d_in[3];
  const float* inw    = (const float*)d_in[4];
  const float* convw  = (const float*)d_in[5];
  const float* convb  = (const float*)d_in[6];
  const float* xpw    = (const float*)d_in[7];
  const float* dtw    = (const float*)d_in[8];
  const float* dtb    = (const float*)d_in[9];
  const float* A_log  = (const float*)d_in[10];
  const float* Dparam = (const float*)d_in[11];
  const float* outw   = (const float*)d_in[12];
  const float* fw1    = (const float*)d_in[13];
  const float* fb1    = (const float*)d_in[14];
  const float* fw2    = (const float*)d_in[15];
  const float* fb2    = (const float*)d_in[16];

  char* ws = (char*)d_ws;
  size_t off = 0;
  auto alloc = [&](size_t bytes) { char* p = ws + off; off += (bytes + 255) & ~255ull; return p; };
  float* gb     = (float*)alloc((size_t)NBATCH*1024*4);
  float* hbuf   = (float*)alloc((size_t)NBATCH*512*4);
  u16*   fgpad  = (u16*)  alloc((size_t)NBATCH*128*512*2);
  float* scores = (float*)alloc((size_t)NBATCH*2048*128*4);
  u16*   xbf    = (u16*)  alloc((size_t)8192*512*2);          // later reused as y bf16
  u16*   inwbf  = (u16*)  alloc((size_t)1024*512*2);
  u16*   outwbf = (u16*)  alloc((size_t)512*512*2);
  u16*   wcomb  = (u16*)  alloc((size_t)640*512*2);
  u16*   xsres  = (u16*)  alloc((size_t)8192*1024*2);         // bf16 xs|res
  u16*   dpp    = (u16*)  alloc(4*DPPLANE*2);                 // bf16 split-K partials
  u16*   dpf    = (u16*)  alloc(DPPLANE*2);                   // final dp bf16
  u16*   ubf    = (u16*)  alloc((size_t)8192*512*2);
  float* Bv     = (float*)alloc((size_t)8192*16*4);
  float* Cv     = (float*)alloc((size_t)8192*16*4);
  u16*   deltaT = (u16*)  alloc((size_t)NBATCH*512*2048*2);
  u16*   slocal = (u16*)  alloc((size_t)NBATCH*NCHUNK*512*16*2);
  float* sumdp  = (float*)alloc((size_t)NBATCH*NCHUNK*512*4);
  u16*   sIn    = (u16*)  alloc((size_t)NBATCH*NCHUNK*512*16*2);
  // disbf (33.5 MB) overlays slocal(16.7)+sumdp(1)+sIn(16.7)=34.4 MB: all dead until after dp GEMM.
  u16*   disbf  = (u16*)slocal;

  film1_kernel<<<dim3(32, NBATCH), 256, 0, stream>>>(gpt, fw1, fb1, hbuf);
  film2_kernel<<<dim3(64, NBATCH), 256, 0, stream>>>(hbuf, fw2, fb2, gb);
  prep_kernel<<<2688 + 16384, 256, 0, stream>>>(fg, inw, outw, dtw, xpw, dis,
                                                fgpad, inwbf, outwbf, wcomb, disbf);

  // scores via MFMA: atoms(fp32) @ fgpad^T per batch (64-row tiles, 128 blocks)
  gemm_f32a64_kernel<<<dim3(1, 2048/64, NBATCH), 256, 0, stream>>>(
      atoms, fgpad, scores, 2048, 128, 512,
      (long long)2048*512, (long long)128*512, (long long)2048*128);
  pv_film_kernel<<<8192/4, 256, 0, stream>>>(atoms, fg, scores, gb, xbf);

  // in_proj: [8192,512] @ [1024,512]^T -> xsres (bf16 out)
  gemm_bt64_kernel<<<dim3(1024/128, 8192/64), 256, 0, stream>>>(
      xbf, inwbf, xsres, 8192, 1024, 512, 2);
  conv_silu_kernel<<<262144/256, 256, 0, stream>>>(xsres, convw, convb, ubf);

  // fused delta/B/C: [8192,512] @ [640,512]^T (64-row tiles, 640 blocks)
  gemm_delta_kernel<<<dim3(640/128, 8192/64), 256, 0, stream>>>(
      ubf, wcomb, dtb, deltaT, Bv, Cv);

  // delta_p: split-K=4, all-bf16, BK=64, per-batch disbf @ deltaT^T -> dpp[4]
  gemm_dpbf_splitk_kernel<<<dim3(512/128, 2048/128, NBATCH*4), 256, 0, stream>>>(
      disbf, deltaT, dpp);

  scanA_kernel<<<dim3(2, NCHUNK, NBATCH), 256, 0, stream>>>(dpp, ubf, Bv, A_log, dpf, slocal, sumdp);
  scanB_kernel<<<32768/64, 64, 0, stream>>>(slocal, sumdp, A_log, sIn);
  u16* ybf = xbf;
  scanC_kernel<<<dim3(2, NCHUNK, NBATCH), 256, 0, stream>>>(dpf, ubf, Bv, Cv, A_log, Dparam, xsres, sIn, ybf);

  // out_proj: [8192,512] @ [512,512]^T -> out (fp32 + finite clamp)
  gemm_bt64_kernel<<<dim3(512/128, 8192/64), 256, 0, stream>>>(
      ybf, outwbf, (float*)d_out, 8192, 512, 512, 1);
}

// Round 16
// 218.761 us; speedup vs baseline: 1.0093x; 1.0093x over previous
//
#include <hip/hip_runtime.h>
#include <stdint.h>

#define D_MODEL 512
#define D_STATE 16
#define DT_RANK 32
#define SEQ 2048
#define NBATCH 4
#define FN 32
#define CHUNK 16
#define NCHUNK 128   // SEQ / CHUNK
#define DPPLANE ((size_t)8192*D_MODEL)   // one split-K partial plane (elements)

typedef unsigned short u16;
using s16x8 = __attribute__((ext_vector_type(8))) short;
using f32x4 = __attribute__((ext_vector_type(4))) float;
using f32x8 = __attribute__((ext_vector_type(8))) float;
using bf16x8 = __attribute__((ext_vector_type(8))) __bf16;

typedef __attribute__((address_space(3))) void lds_void;
typedef __attribute__((address_space(1))) const void glb_void;

__device__ __forceinline__ void gload16(const void* g, void* l) {
  __builtin_amdgcn_global_load_lds((glb_void*)g, (lds_void*)l, 16, 0, 0);
}

__device__ inline u16 f2bf(float f) {
  uint32_t u = __float_as_uint(f);
  u += 0x7FFFu + ((u >> 16) & 1u);   // RNE
  return (u16)(u >> 16);
}
__device__ __forceinline__ float bf2f(u16 v) {
  return __uint_as_float((uint32_t)v << 16);
}

// HW packed convert: 2×float4 -> 8 bf16 (v_cvt_pk_bf16_f32, RNE)
__device__ __forceinline__ s16x8 pack8bf(float4 lo, float4 hi) {
  f32x8 v;
  v[0] = lo.x; v[1] = lo.y; v[2] = lo.z; v[3] = lo.w;
  v[4] = hi.x; v[5] = hi.y; v[6] = hi.z; v[7] = hi.w;
  bf16x8 b = __builtin_convertvector(v, bf16x8);
  return __builtin_bit_cast(s16x8, b);
}
__device__ __forceinline__ ushort4 pack4bf(float a, float b, float c, float d) {
  ushort4 o; o.x = f2bf(a); o.y = f2bf(b); o.z = f2bf(c); o.w = f2bf(d);
  return o;
}

// ---------------- FiLM stage 1: h = silu(gpt @ w1^T + b1) ----------------
__global__ __launch_bounds__(256) void film1_kernel(
    const float* __restrict__ gpt, const float* __restrict__ w1,
    const float* __restrict__ b1, float* __restrict__ h)
{
  int b = blockIdx.y, r0 = blockIdx.x*16, t = threadIdx.x;
  __shared__ float g[D_MODEL];
  for (int i = t; i < D_MODEL; i += 256) g[i] = gpt[b*D_MODEL + i];
  __syncthreads();
  int r = r0 + (t >> 4), ln = t & 15;
  const float* wr = &w1[(size_t)r*D_MODEL + ln*32];
  const float* gg = &g[ln*32];
  float s = 0.f;
  #pragma unroll
  for (int k = 0; k < 32; k += 4) {
    float4 w = *(const float4*)&wr[k];
    s += w.x*gg[k] + w.y*gg[k+1] + w.z*gg[k+2] + w.w*gg[k+3];
  }
  s += __shfl_down(s, 8); s += __shfl_down(s, 4);
  s += __shfl_down(s, 2); s += __shfl_down(s, 1);
  if (ln == 0) { float v = s + b1[r]; h[b*D_MODEL + r] = v / (1.f + expf(-v)); }
}

// ---------------- FiLM stage 2: gb = h @ w2^T + b2 (gamma|beta) ----------------
__global__ __launch_bounds__(256) void film2_kernel(
    const float* __restrict__ h, const float* __restrict__ w2,
    const float* __restrict__ b2, float* __restrict__ gb)
{
  int b = blockIdx.y, r0 = blockIdx.x*16, t = threadIdx.x;
  __shared__ float hs[D_MODEL];
  for (int i = t; i < D_MODEL; i += 256) hs[i] = h[b*D_MODEL + i];
  __syncthreads();
  int r = r0 + (t >> 4), ln = t & 15;
  const float* wr = &w2[(size_t)r*D_MODEL + ln*32];
  const float* gg = &hs[ln*32];
  float s = 0.f;
  #pragma unroll
  for (int k = 0; k < 32; k += 4) {
    float4 w = *(const float4*)&wr[k];
    s += w.x*gg[k] + w.y*gg[k+1] + w.z*gg[k+2] + w.w*gg[k+3];
  }
  s += __shfl_down(s, 8); s += __shfl_down(s, 4);
  s += __shfl_down(s, 2); s += __shfl_down(s, 1);
  if (ln == 0) gb[b*1024 + r] = s + b2[r];
}

// ---------------- merged prep: fgpad | inwbf | outwbf | wcomb | dis->bf16 ----------------
__global__ __launch_bounds__(256) void prep_kernel(
    const float* __restrict__ fg, const float* __restrict__ inw,
    const float* __restrict__ outw, const float* __restrict__ dtw,
    const float* __restrict__ xpw, const float* __restrict__ dis,
    u16* __restrict__ fgpad, u16* __restrict__ inwbf,
    u16* __restrict__ outwbf, u16* __restrict__ wcomb,
    u16* __restrict__ disbf)
{
  int blk = blockIdx.x, t = threadIdx.x;
  if (blk >= 2688) {                     // dis f32 -> bf16, 16384 blocks
    size_t i = (size_t)(blk - 2688)*256 + t;
    float4 v = *(const float4*)&dis[i*4];
    ushort4 o; o.x = f2bf(v.x); o.y = f2bf(v.y); o.z = f2bf(v.z); o.w = f2bf(v.w);
    *(ushort4*)&disbf[i*4] = o;
  } else if (blk < 512) {                // fgpad: [b][128][512], zero-padded
    int row = blk & 127, b = blk >> 7;
    u16* dst = &fgpad[((size_t)b*128 + row)*D_MODEL];
    if (row < FN) {
      const float* src = &fg[((size_t)b*FN + row)*D_MODEL];
      float2 v = *(const float2*)&src[t*2];
      dst[t*2] = f2bf(v.x); dst[t*2+1] = f2bf(v.y);
    } else {
      dst[t*2] = 0; dst[t*2+1] = 0;
    }
  } else if (blk < 1536) {               // inwbf
    int row = blk - 512;
    float2 v = *(const float2*)&inw[(size_t)row*D_MODEL + t*2];
    inwbf[(size_t)row*D_MODEL + t*2]     = f2bf(v.x);
    inwbf[(size_t)row*D_MODEL + t*2 + 1] = f2bf(v.y);
  } else if (blk < 2048) {               // outwbf
    int row = blk - 1536;
    float2 v = *(const float2*)&outw[(size_t)row*D_MODEL + t*2];
    outwbf[(size_t)row*D_MODEL + t*2]     = f2bf(v.x);
    outwbf[(size_t)row*D_MODEL + t*2 + 1] = f2bf(v.y);
  } else {                               // wcomb
    int row = blk - 2048;
    if (row < D_MODEL) {
      __shared__ float dr[DT_RANK];
      if (t < DT_RANK) dr[t] = dtw[row*DT_RANK + t];
      __syncthreads();
      for (int k = t; k < D_MODEL; k += 256) {
        float s = 0.f;
        #pragma unroll
        for (int r = 0; r < DT_RANK; r++) s += dr[r] * xpw[r*D_MODEL + k];
        wcomb[(size_t)row*D_MODEL + k] = f2bf(s);
      }
    } else if (row < D_MODEL + 32) {
      for (int k = t; k < D_MODEL; k += 256)
        wcomb[(size_t)row*D_MODEL + k] = f2bf(xpw[(size_t)(DT_RANK + row - D_MODEL)*D_MODEL + k]);
    } else {
      for (int k = t; k < D_MODEL; k += 256)
        wcomb[(size_t)row*D_MODEL + k] = 0;
    }
  }
}

// ---------------- softmax + PV + residual + FiLM -> x bf16, one wave per row ----------------
__global__ __launch_bounds__(256) void pv_film_kernel(
    const float* __restrict__ atoms, const float* __restrict__ fg,
    const float* __restrict__ scores, const float* __restrict__ gb,
    u16* __restrict__ xout)
{
  int wave = threadIdx.x >> 6, lane = threadIdx.x & 63;
  int row = blockIdx.x*4 + wave;           // b*SEQ + l
  int b = row >> 11;
  float s = scores[(size_t)row*128 + (lane & 31)] * 0.04419417382415922f; // 1/sqrt(512)
  float m = s;
  #pragma unroll
  for (int o = 16; o; o >>= 1) m = fmaxf(m, __shfl_xor(m, o));
  float e = __expf(s - m);
  float sum = e;
  #pragma unroll
  for (int o = 16; o; o >>= 1) sum += __shfl_xor(sum, o);
  float my_attn = e / sum;                 // attn[lane&31]

  int d0 = lane*8;
  const float* arow = &atoms[(size_t)row*D_MODEL + d0];
  float4 acc0 = *(const float4*)&arow[0];
  float4 acc1 = *(const float4*)&arow[4];
  const float* fgb = &fg[(size_t)b*FN*D_MODEL + d0];
  #pragma unroll 8
  for (int f = 0; f < FN; f++) {
    float w = __shfl(my_attn, f);          // broadcast attn[f]
    float4 g0 = *(const float4*)&fgb[(size_t)f*D_MODEL];
    float4 g1 = *(const float4*)&fgb[(size_t)f*D_MODEL + 4];
    acc0.x += w*g0.x; acc0.y += w*g0.y; acc0.z += w*g0.z; acc0.w += w*g0.w;
    acc1.x += w*g1.x; acc1.y += w*g1.y; acc1.z += w*g1.z; acc1.w += w*g1.w;
  }
  const float* gbg = &gb[(size_t)b*1024 + d0];
  float4 gm0 = *(const float4*)&gbg[0];
  float4 gm1 = *(const float4*)&gbg[4];
  float4 bt0 = *(const float4*)&gbg[D_MODEL];
  float4 bt1 = *(const float4*)&gbg[D_MODEL + 4];
  s16x8 o;
  o[0] = (short)f2bf(acc0.x*gm0.x + bt0.x);
  o[1] = (short)f2bf(acc0.y*gm0.y + bt0.y);
  o[2] = (short)f2bf(acc0.z*gm0.z + bt0.z);
  o[3] = (short)f2bf(acc0.w*gm0.w + bt0.w);
  o[4] = (short)f2bf(acc1.x*gm1.x + bt1.x);
  o[5] = (short)f2bf(acc1.y*gm1.y + bt1.y);
  o[6] = (short)f2bf(acc1.z*gm1.z + bt1.z);
  o[7] = (short)f2bf(acc1.w*gm1.w + bt1.w);
  *(s16x8*)&xout[(size_t)row*D_MODEL + d0] = o;
}

// ---------------- bf16 GEMM 64x128 tile, 2-phase dbuf; outMode: 0=f32,1=f32+clamp,2=bf16 ----------------
__global__ __launch_bounds__(256) void gemm_bt64_kernel(
    const u16* __restrict__ A, const u16* __restrict__ B, void* __restrict__ Cv_,
    int M, int N, int K, int outMode)
{
  int gx = gridDim.x, gy = gridDim.y;
  int flat = blockIdx.x + gx*blockIdx.y;
  int cpx = (gx*gy) >> 3;
  flat = (flat & 7)*cpx + (flat >> 3);
  int bx = flat % gx, by = flat / gx;
  int m0 = by * 64, n0 = bx * 128;
  __shared__ u16 As[2][64][32];
  __shared__ u16 Bs[2][128][32];
  int tid = threadIdx.x, lane = tid & 63, wave = tid >> 6;
  int wm = (wave >> 1) * 32, wn = (wave & 1) * 64;
  int fr = lane & 15, fk = (lane >> 4) * 8;
  int srow = tid >> 2, scol = (tid & 3) * 8;
  const u16* abase  = &A[(size_t)(m0 + srow)*K + scol];
  const u16* b0base = &B[(size_t)(n0 + srow)*K + scol];
  const u16* b1base = &B[(size_t)(n0 + 64 + srow)*K + scol];
  gload16(abase,  &As[0][srow][scol]);
  gload16(b0base, &Bs[0][srow][scol]);
  gload16(b1base, &Bs[0][64 + srow][scol]);
  __syncthreads();
  f32x4 acc[2][4] = {};
  int NT = K >> 5, cur = 0;
  for (int t = 0; t < NT; t++) {
    int nxt = cur ^ 1;
    if (t + 1 < NT) {
      int k0 = (t + 1) << 5;
      gload16(&abase[k0],  &As[nxt][srow][scol]);
      gload16(&b0base[k0], &Bs[nxt][srow][scol]);
      gload16(&b1base[k0], &Bs[nxt][64 + srow][scol]);
    }
    s16x8 af[2], bf[4];
    #pragma unroll
    for (int i = 0; i < 2; i++) af[i] = *(const s16x8*)(&As[cur][wm + i*16 + fr][fk]);
    #pragma unroll
    for (int i = 0; i < 4; i++) bf[i] = *(const s16x8*)(&Bs[cur][wn + i*16 + fr][fk]);
    #pragma unroll
    for (int mi = 0; mi < 2; mi++)
      #pragma unroll
      for (int ni = 0; ni < 4; ni++)
        acc[mi][ni] = __builtin_amdgcn_mfma_f32_16x16x32_bf16(af[mi], bf[ni], acc[mi][ni], 0, 0, 0);
    __syncthreads();
    cur = nxt;
  }
  int cr = (lane >> 4) * 4, cc = lane & 15;
  if (outMode == 2) {
    u16* C = (u16*)Cv_;
    #pragma unroll
    for (int mi = 0; mi < 2; mi++)
      #pragma unroll
      for (int ni = 0; ni < 4; ni++) {
        int rowb = m0 + wm + mi*16 + cr, col = n0 + wn + ni*16 + cc;
        #pragma unroll
        for (int r = 0; r < 4; r++)
          C[(size_t)(rowb + r)*N + col] = f2bf(acc[mi][ni][r]);
      }
  } else {
    float* C = (float*)Cv_;
    #pragma unroll
    for (int mi = 0; mi < 2; mi++)
      #pragma unroll
      for (int ni = 0; ni < 4; ni++) {
        int rowb = m0 + wm + mi*16 + cr, col = n0 + wn + ni*16 + cc;
        #pragma unroll
        for (int r = 0; r < 4; r++) {
          float v = acc[mi][ni][r];
          if (outMode == 1 && !isfinite(v)) v = 0.f;
          C[(size_t)(rowb + r)*N + col] = v;
        }
      }
  }
}

// ---------------- scores GEMM: fp32 A, 64-row tiles (better occupancy) ----------------
__global__ __launch_bounds__(256) void gemm_f32a64_kernel(
    const float* __restrict__ Ag, const u16* __restrict__ Bg, float* __restrict__ Cg,
    int M, int N, int K, long long azs, long long bzs, long long czs)
{
  int gx = gridDim.x, gy = gridDim.y;
  int flat = blockIdx.x + gx*(blockIdx.y + gy*blockIdx.z);
  int cpx = (gx*gy*(int)gridDim.z) >> 3;
  flat = (flat & 7)*cpx + (flat >> 3);
  int bx = flat % gx, tmp = flat / gx;
  int by = tmp % gy, bz = tmp / gy;
  const float* A = Ag + (size_t)bz * azs;
  const u16* B = Bg + (size_t)bz * bzs;
  float* C = Cg + (size_t)bz * czs;
  int m0 = by * 64, n0 = bx * 128;
  __shared__ u16 As[64][32];
  __shared__ u16 Bs[128][32];
  int tid = threadIdx.x, lane = tid & 63, wave = tid >> 6;
  int wm = (wave >> 1) * 32, wn = (wave & 1) * 64;
  int fr = lane & 15, fk = (lane >> 4) * 8;
  int srow = tid >> 2, scol = (tid & 3) * 8;
  f32x4 acc[2][4] = {};
  for (int k0 = 0; k0 < K; k0 += 32) {
    const float* ap = &A[(size_t)(m0 + srow)*K + k0 + scol];
    float4 a0 = *(const float4*)&ap[0];
    float4 a1 = *(const float4*)&ap[4];
    gload16(&B[(size_t)(n0 + srow)*K + k0 + scol],      &Bs[srow][scol]);
    gload16(&B[(size_t)(n0 + 64 + srow)*K + k0 + scol], &Bs[64 + srow][scol]);
    *(s16x8*)&As[srow][scol] = pack8bf(a0, a1);
    __syncthreads();
    s16x8 af[2], bf[4];
    #pragma unroll
    for (int i = 0; i < 2; i++) af[i] = *(const s16x8*)(&As[wm + i*16 + fr][fk]);
    #pragma unroll
    for (int i = 0; i < 4; i++) bf[i] = *(const s16x8*)(&Bs[wn + i*16 + fr][fk]);
    #pragma unroll
    for (int mi = 0; mi < 2; mi++)
      #pragma unroll
      for (int ni = 0; ni < 4; ni++)
        acc[mi][ni] = __builtin_amdgcn_mfma_f32_16x16x32_bf16(af[mi], bf[ni], acc[mi][ni], 0, 0, 0);
    __syncthreads();
  }
  int cr = (lane >> 4) * 4, cc = lane & 15;
  #pragma unroll
  for (int mi = 0; mi < 2; mi++)
    #pragma unroll
    for (int ni = 0; ni < 4; ni++) {
      int rowb = m0 + wm + mi*16 + cr, col = n0 + wn + ni*16 + cc;
      #pragma unroll
      for (int r = 0; r < 4; r++)
        C[(size_t)(rowb + r)*N + col] = acc[mi][ni][r];
    }
}

// ---------------- delta_p split-K=2 GEMM, all-bf16, BK=64 (32KB LDS) ----------------
// grid: (4 n-tiles, 16 m-tiles, 8 = b*2 + ks), each block K-slice of 1024
__global__ __launch_bounds__(256) void gemm_dpbf_splitk_kernel(
    const u16* __restrict__ disbf, const u16* __restrict__ deltaT,
    u16* __restrict__ dpp)
{
  int gx = gridDim.x, gy = gridDim.y;
  int flat = blockIdx.x + gx*(blockIdx.y + gy*blockIdx.z);
  int cpx = (gx*gy*(int)gridDim.z) >> 3;
  flat = (flat & 7)*cpx + (flat >> 3);
  int bx = flat % gx, tmp = flat / gx;
  int by = tmp % gy, bz = tmp / gy;
  int b = bz >> 1, ks = bz & 1;
  const u16* A = disbf  + (size_t)b*SEQ*SEQ     + ks*1024;
  const u16* B = deltaT + (size_t)b*D_MODEL*SEQ + ks*1024;
  u16*       C = dpp    + (size_t)ks*DPPLANE    + (size_t)b*SEQ*D_MODEL;
  int m0 = by * 128, n0 = bx * 128;
  __shared__ u16 As[128][64];
  __shared__ u16 Bs[128][64];
  int tid = threadIdx.x, lane = tid & 63, wave = tid >> 6;
  int wm = (wave >> 1) * 64, wn = (wave & 1) * 64;
  int fr = lane & 15, fk = (lane >> 4) * 8;
  int srow = tid >> 3, scol = (tid & 7) * 8;     // 32 rows / issue, 64-col rows
  f32x4 acc[4][4] = {};
  for (int k0 = 0; k0 < 1024; k0 += 64) {
    #pragma unroll
    for (int i = 0; i < 4; i++) {
      gload16(&A[(size_t)(m0 + srow + 32*i)*SEQ + k0 + scol], &As[srow + 32*i][scol]);
      gload16(&B[(size_t)(n0 + srow + 32*i)*SEQ + k0 + scol], &Bs[srow + 32*i][scol]);
    }
    __syncthreads();
    #pragma unroll
    for (int kk = 0; kk < 64; kk += 32) {
      s16x8 af[4], bf[4];
      #pragma unroll
      for (int i = 0; i < 4; i++) af[i] = *(const s16x8*)(&As[wm + i*16 + fr][kk + fk]);
      #pragma unroll
      for (int i = 0; i < 4; i++) bf[i] = *(const s16x8*)(&Bs[wn + i*16 + fr][kk + fk]);
      #pragma unroll
      for (int mi = 0; mi < 4; mi++)
        #pragma unroll
        for (int ni = 0; ni < 4; ni++)
          acc[mi][ni] = __builtin_amdgcn_mfma_f32_16x16x32_bf16(af[mi], bf[ni], acc[mi][ni], 0, 0, 0);
    }
    __syncthreads();
  }
  int cr = (lane >> 4) * 4, cc = lane & 15;
  #pragma unroll
  for (int mi = 0; mi < 4; mi++)
    #pragma unroll
    for (int ni = 0; ni < 4; ni++) {
      int rowb = m0 + wm + mi*16 + cr, col = n0 + wn + ni*16 + cc;
      #pragma unroll
      for (int r = 0; r < 4; r++)
        C[(size_t)(rowb + r)*D_MODEL + col] = f2bf(acc[mi][ni][r]);
    }
}

// ---------------- fused delta/B/C GEMM (64-row tiles): ubf @ Wcomb^T ----------------
__global__ __launch_bounds__(256) void gemm_delta_kernel(
    const u16* __restrict__ A, const u16* __restrict__ B,
    const float* __restrict__ dtb, u16* __restrict__ deltaT,
    float* __restrict__ Bv, float* __restrict__ Cv)
{
  int gx = gridDim.x, gy = gridDim.y;   // (5, 128)
  int flat = blockIdx.x + gx*blockIdx.y;
  int cpx = (gx*gy) >> 3;
  flat = (flat & 7)*cpx + (flat >> 3);
  int bx = flat % gx, by = flat / gx;
  int m0 = by * 64, n0 = bx * 128;
  __shared__ u16 As[64][32];
  __shared__ u16 Bs[128][32];
  int tid = threadIdx.x, lane = tid & 63, wave = tid >> 6;
  int wm = (wave >> 1) * 32, wn = (wave & 1) * 64;
  int fr = lane & 15, fk = (lane >> 4) * 8;
  int srow = tid >> 2, scol = (tid & 3) * 8;
  f32x4 acc[2][4] = {};
  for (int k0 = 0; k0 < D_MODEL; k0 += 32) {
    gload16(&A[(size_t)(m0 + srow)*D_MODEL + k0 + scol],      &As[srow][scol]);
    gload16(&B[(size_t)(n0 + srow)*D_MODEL + k0 + scol],      &Bs[srow][scol]);
    gload16(&B[(size_t)(n0 + 64 + srow)*D_MODEL + k0 + scol], &Bs[64 + srow][scol]);
    __syncthreads();
    s16x8 af[2], bf[4];
    #pragma unroll
    for (int i = 0; i < 2; i++) af[i] = *(const s16x8*)(&As[wm + i*16 + fr][fk]);
    #pragma unroll
    for (int i = 0; i < 4; i++) bf[i] = *(const s16x8*)(&Bs[wn + i*16 + fr][fk]);
    #pragma unroll
    for (int mi = 0; mi < 2; mi++)
      #pragma unroll
      for (int ni = 0; ni < 4; ni++)
        acc[mi][ni] = __builtin_amdgcn_mfma_f32_16x16x32_bf16(af[mi], bf[ni], acc[mi][ni], 0, 0, 0);
    __syncthreads();
  }
  int cr = (lane >> 4) * 4, cc = lane & 15;
  #pragma unroll
  for (int mi = 0; mi < 2; mi++)
    #pragma unroll
    for (int ni = 0; ni < 4; ni++) {
      int rowb = m0 + wm + mi*16 + cr, col = n0 + wn + ni*16 + cc;
      if (col < D_MODEL) {
        float bias = dtb[col];
        #pragma unroll
        for (int r = 0; r < 4; r++) {
          float v = acc[mi][ni][r] + bias;
          v = (v > 20.f) ? v : log1pf(expf(v));
          int gr = rowb + r;
          deltaT[((size_t)(gr >> 11)*D_MODEL + col)*SEQ + (gr & (SEQ-1))] = f2bf(v);
        }
      } else if (col < D_MODEL + 16) {
        #pragma unroll
        for (int r = 0; r < 4; r++)
          Bv[(size_t)(rowb + r)*D_STATE + (col - D_MODEL)] = acc[mi][ni][r];
      } else if (col < D_MODEL + 32) {
        #pragma unroll
        for (int r = 0; r < 4; r++)
          Cv[(size_t)(rowb + r)*D_STATE + (col - D_MODEL - 16)] = acc[mi][ni][r];
      }
    }
}

// ---------------- depthwise causal conv + silu, 4 rows/thread (register reuse) ----------------
__global__ __launch_bounds__(256) void conv_silu_kernel(
    const u16* __restrict__ xsres, const float* __restrict__ cw,
    const float* __restrict__ cb, u16* __restrict__ ubf)
{
  int idx = blockIdx.x*256 + threadIdx.x;     // 262144 threads
  int dq = idx & 127;                         // d-quad
  int rg = idx >> 7;                          // row-group: rows 4rg..4rg+3
  int d = dq*4;
  size_t row0 = (size_t)rg*4;
  int l0 = (int)(row0 & (SEQ - 1));           // within-batch l of first row
  float w[4][4];
  #pragma unroll
  for (int c = 0; c < 4; c++) *(float4*)w[c] = *(const float4*)&cw[(d + c)*4];
  float4 bias = *(const float4*)&cb[d];
  float4 x[7];                                // rows l0-3 .. l0+3
  #pragma unroll
  for (int k = 0; k < 7; k++) {
    int li = l0 - 3 + k;
    if (li >= 0) {
      ushort4 v = *(const ushort4*)&xsres[(row0 - 3 + k)*1024 + d];
      x[k] = make_float4(bf2f(v.x), bf2f(v.y), bf2f(v.z), bf2f(v.w));
    } else {
      x[k] = make_float4(0.f, 0.f, 0.f, 0.f);
    }
  }
  #pragma unroll
  for (int j = 0; j < 4; j++) {
    float4 acc = bias;
    #pragma unroll
    for (int k = 0; k < 4; k++) {
      float4 v = x[j + k];
      acc.x += v.x*w[0][k]; acc.y += v.y*w[1][k];
      acc.z += v.z*w[2][k]; acc.w += v.w*w[3][k];
    }
    float4 o;
    o.x = acc.x/(1.f+expf(-acc.x)); o.y = acc.y/(1.f+expf(-acc.y));
    o.z = acc.z/(1.f+expf(-acc.z)); o.w = acc.w/(1.f+expf(-acc.w));
    ushort4 ob; ob.x = f2bf(o.x); ob.y = f2bf(o.y); ob.z = f2bf(o.z); ob.w = f2bf(o.w);
    *(ushort4*)&ubf[(row0 + j)*D_MODEL + d] = ob;
  }
}

// ---------------- scan phase A: sum bf16 split-K partials -> dpf(bf16), local state + sum(dp) ----------------
__global__ __launch_bounds__(256) void scanA_kernel(
    const u16* __restrict__ dpp, const u16* __restrict__ ubf,
    const float* __restrict__ Bv, const float* __restrict__ A_log,
    u16* __restrict__ dpf, u16* __restrict__ slocal, float* __restrict__ sumdp_out)
{
  int d = blockIdx.x*256 + threadIdx.x;
  int c = blockIdx.y, b = blockIdx.z;
  __shared__ float Bs[CHUNK][D_STATE];
  int t = threadIdx.x;
  size_t lbase = (size_t)b*SEQ + c*CHUNK;
  Bs[t >> 4][t & 15] = Bv[(lbase + (t >> 4))*D_STATE + (t & 15)];
  float a[D_STATE];
  #pragma unroll
  for (int n = 0; n < D_STATE; n += 4) {
    float4 v = *(const float4*)&A_log[(size_t)d*D_STATE + n];
    a[n] = -expf(v.x); a[n+1] = -expf(v.y); a[n+2] = -expf(v.z); a[n+3] = -expf(v.w);
  }
  __syncthreads();
  float s[D_STATE];
  #pragma unroll
  for (int n = 0; n < D_STATE; n++) s[n] = 0.f;
  float sd = 0.f;
  for (int j = 0; j < CHUNK; j++) {
    size_t r = lbase + j;
    size_t idx = r*D_MODEL + d;
    float dpv = bf2f(dpp[idx]) + bf2f(dpp[idx + DPPLANE]);
    dpf[idx] = f2bf(dpv);
    float uv  = bf2f(ubf[idx]);
    sd += dpv;
    float dbu = dpv * uv;
    #pragma unroll
    for (int n = 0; n < D_STATE; n++)
      s[n] = __expf(a[n]*dpv)*s[n] + dbu*Bs[j][n];
  }
  size_t obase = ((size_t)b*NCHUNK + c)*D_MODEL + d;
  #pragma unroll
  for (int n = 0; n < D_STATE; n += 4)
    *(ushort4*)&slocal[obase*D_STATE + n] = pack4bf(s[n], s[n+1], s[n+2], s[n+3]);
  sumdp_out[obase] = sd;
}

// ---------------- scan phase B: propagate chunk carries (bf16 in/out), 64-thr blocks ----------------
__global__ __launch_bounds__(64) void scanB_kernel(
    const u16* __restrict__ slocal, const float* __restrict__ sumdp,
    const float* __restrict__ A_log, u16* __restrict__ sIn)
{
  int g = blockIdx.x*64 + threadIdx.x;    // 32768 = b*8192 + d*16 + n
  int n = g & 15, d = (g >> 4) & (D_MODEL - 1), b = g >> 13;
  float a = -expf(A_log[d*D_STATE + n]);
  float s = 0.f;
  for (int c = 0; c < NCHUNK; c++) {
    size_t idx = ((size_t)b*NCHUNK + c)*D_MODEL + d;
    sIn[idx*D_STATE + n] = f2bf(s);
    s = __expf(a * sumdp[idx]) * s + bf2f(slocal[idx*D_STATE + n]);
  }
}

// ---------------- scan phase C: outputs + gating, writes y bf16 ----------------
__global__ __launch_bounds__(256) void scanC_kernel(
    const u16* __restrict__ dp, const u16* __restrict__ ubf,
    const float* __restrict__ Bv, const float* __restrict__ Cv,
    const float* __restrict__ A_log, const float* __restrict__ Dp,
    const u16* __restrict__ xsres, const u16* __restrict__ sIn,
    u16* __restrict__ yout)
{
  int d = blockIdx.x*256 + threadIdx.x;
  int c = blockIdx.y, b = blockIdx.z;
  __shared__ float Bs[CHUNK][D_STATE];
  __shared__ float Cs[CHUNK][D_STATE];
  int t = threadIdx.x;
  size_t lbase = (size_t)b*SEQ + c*CHUNK;
  Bs[t >> 4][t & 15] = Bv[(lbase + (t >> 4))*D_STATE + (t & 15)];
  Cs[t >> 4][t & 15] = Cv[(lbase + (t >> 4))*D_STATE + (t & 15)];
  float a[D_STATE];
  #pragma unroll
  for (int n = 0; n < D_STATE; n += 4) {
    float4 v = *(const float4*)&A_log[(size_t)d*D_STATE + n];
    a[n] = -expf(v.x); a[n+1] = -expf(v.y); a[n+2] = -expf(v.z); a[n+3] = -expf(v.w);
  }
  float s[D_STATE];
  size_t ibase = (((size_t)b*NCHUNK + c)*D_MODEL + d)*D_STATE;
  #pragma unroll
  for (int n = 0; n < D_STATE; n += 4) {
    ushort4 v = *(const ushort4*)&sIn[ibase + n];
    s[n] = bf2f(v.x); s[n+1] = bf2f(v.y); s[n+2] = bf2f(v.z); s[n+3] = bf2f(v.w);
  }
  float dparam = Dp[d];
  __syncthreads();
  for (int j = 0; j < CHUNK; j++) {
    size_t r = lbase + j;
    float dpv = bf2f(dp[r*D_MODEL + d]);
    float uv  = bf2f(ubf[r*D_MODEL + d]);
    float dbu = dpv * uv;
    float y = 0.f;
    #pragma unroll
    for (int n = 0; n < D_STATE; n++) {
      s[n] = __expf(a[n]*dpv)*s[n] + dbu*Bs[j][n];
      y += s[n]*Cs[j][n];
    }
    y += uv * dparam;
    float rr = bf2f(xsres[r*1024 + D_MODEL + d]);
    y *= rr/(1.f + __expf(-rr));       // silu(res)
    yout[r*D_MODEL + d] = f2bf(y);
  }
}

extern "C" void kernel_launch(void* const* d_in, const int* in_sizes, int n_in,
                              void* d_out, int out_size, void* d_ws, size_t ws_size,
                              hipStream_t stream)
{
  const float* atoms  = (const float*)d_in[0];
  const float* dis    = (const float*)d_in[1];
  const float* gpt    = (const float*)d_in[2];
  const float* fg     = (const float*)d_in[3];
  const float* inw    = (const float*)d_in[4];
  const float* convw  = (const float*)d_in[5];
  const float* convb  = (const float*)d_in[6];
  const float* xpw    = (const float*)d_in[7];
  const float* dtw    = (const float*)d_in[8];
  const float* dtb    = (const float*)d_in[9];
  const float* A_log  = (const float*)d_in[10];
  const float* Dparam = (const float*)d_in[11];
  const float* outw   = (const float*)d_in[12];
  const float* fw1    = (const float*)d_in[13];
  const float* fb1    = (const float*)d_in[14];
  const float* fw2    = (const float*)d_in[15];
  const float* fb2    = (const float*)d_in[16];

  char* ws = (char*)d_ws;
  size_t off = 0;
  auto alloc = [&](size_t bytes) { char* p = ws + off; off += (bytes + 255) & ~255ull; return p; };
  float* gb     = (float*)alloc((size_t)NBATCH*1024*4);
  float* hbuf   = (float*)alloc((size_t)NBATCH*512*4);
  u16*   fgpad  = (u16*)  alloc((size_t)NBATCH*128*512*2);
  float* scores = (float*)alloc((size_t)NBATCH*2048*128*4);
  u16*   xbf    = (u16*)  alloc((size_t)8192*512*2);          // later reused as y bf16
  u16*   inwbf  = (u16*)  alloc((size_t)1024*512*2);
  u16*   outwbf = (u16*)  alloc((size_t)512*512*2);
  u16*   wcomb  = (u16*)  alloc((size_t)640*512*2);
  u16*   xsres  = (u16*)  alloc((size_t)8192*1024*2);         // bf16 xs|res
  u16*   dpp    = (u16*)  alloc(2*DPPLANE*2);                 // bf16 split-K=2 partials
  u16*   dpf    = (u16*)  alloc(DPPLANE*2);                   // final dp bf16
  u16*   ubf    = (u16*)  alloc((size_t)8192*512*2);
  float* Bv     = (float*)alloc((size_t)8192*16*4);
  float* Cv     = (float*)alloc((size_t)8192*16*4);
  u16*   deltaT = (u16*)  alloc((size_t)NBATCH*512*2048*2);
  u16*   slocal = (u16*)  alloc((size_t)NBATCH*NCHUNK*512*16*2);
  float* sumdp  = (float*)alloc((size_t)NBATCH*NCHUNK*512*4);
  u16*   sIn    = (u16*)  alloc((size_t)NBATCH*NCHUNK*512*16*2);
  // disbf (33.5 MB) overlays slocal(16.7)+sumdp(1)+sIn(16.7)=34.4 MB: all dead until after dp GEMM.
  u16*   disbf  = (u16*)slocal;

  film1_kernel<<<dim3(32, NBATCH), 256, 0, stream>>>(gpt, fw1, fb1, hbuf);
  film2_kernel<<<dim3(64, NBATCH), 256, 0, stream>>>(hbuf, fw2, fb2, gb);
  prep_kernel<<<2688 + 16384, 256, 0, stream>>>(fg, inw, outw, dtw, xpw, dis,
                                                fgpad, inwbf, outwbf, wcomb, disbf);

  // scores via MFMA: atoms(fp32) @ fgpad^T per batch (64-row tiles, 128 blocks)
  gemm_f32a64_kernel<<<dim3(1, 2048/64, NBATCH), 256, 0, stream>>>(
      atoms, fgpad, scores, 2048, 128, 512,
      (long long)2048*512, (long long)128*512, (long long)2048*128);
  pv_film_kernel<<<8192/4, 256, 0, stream>>>(atoms, fg, scores, gb, xbf);

  // in_proj: [8192,512] @ [1024,512]^T -> xsres (bf16 out)
  gemm_bt64_kernel<<<dim3(1024/128, 8192/64), 256, 0, stream>>>(
      xbf, inwbf, xsres, 8192, 1024, 512, 2);
  conv_silu_kernel<<<262144/256, 256, 0, stream>>>(xsres, convw, convb, ubf);

  // fused delta/B/C: [8192,512] @ [640,512]^T (64-row tiles, 640 blocks)
  gemm_delta_kernel<<<dim3(640/128, 8192/64), 256, 0, stream>>>(
      ubf, wcomb, dtb, deltaT, Bv, Cv);

  // delta_p: split-K=2, all-bf16, BK=64, per-batch disbf @ deltaT^T -> dpp[2]
  gemm_dpbf_splitk_kernel<<<dim3(512/128, 2048/128, NBATCH*2), 256, 0, stream>>>(
      disbf, deltaT, dpp);

  scanA_kernel<<<dim3(2, NCHUNK, NBATCH), 256, 0, stream>>>(dpp, ubf, Bv, A_log, dpf, slocal, sumdp);
  scanB_kernel<<<32768/64, 64, 0, stream>>>(slocal, sumdp, A_log, sIn);
  u16* ybf = xbf;
  scanC_kernel<<<dim3(2, NCHUNK, NBATCH), 256, 0, stream>>>(dpf, ubf, Bv, Cv, A_log, Dparam, xsres, sIn, ybf);

  // out_proj: [8192,512] @ [512,512]^T -> out (fp32 + finite clamp)
  gemm_bt64_kernel<<<dim3(512/128, 8192/64), 256, 0, stream>>>(
      ybf, outwbf, (float*)d_out, 8192, 512, 512, 1);
}